// Round 1
// baseline (1943.102 us; speedup 1.0000x reference)
//
#include <hip/hip_runtime.h>
#include <math.h>

// Problem constants
#define Bc   8
#define Qn   256
#define Cn   192
#define Hn   20
#define Dn   64
#define En   1500
#define In   5120
#define HIDn 1280
#define BQ   2048            // B*Q rows
#define KSELF 448            // Q + C
#define S1   (BQ*HIDn)       // 2,621,440 floats
#define SI   ((size_t)BQ*In) // 10,485,760 floats
// ws requirement: (4*S1 + SI)*4 bytes = 83.9 MB

typedef __attribute__((ext_vector_type(8))) short bf16x8;
typedef __attribute__((ext_vector_type(4))) float f32x4;

__device__ __forceinline__ short f2bf(float f) {
  union { float f; unsigned u; } x; x.f = f;
  unsigned r = x.u + 0x7fffu + ((x.u >> 16) & 1u);   // round-to-nearest-even
  return (short)(r >> 16);
}

// ---------------------------------------------------------------------------
// LayerNorm: one 256-thread block per row of 1280
// ---------------------------------------------------------------------------
__global__ __launch_bounds__(256) void layernorm_k(
    const float* __restrict__ in, const float* __restrict__ w,
    const float* __restrict__ b, float* __restrict__ out)
{
  const int row = blockIdx.x;
  const float* x = in + (size_t)row * HIDn;
  float v[5], s = 0.f, s2 = 0.f;
#pragma unroll
  for (int i = 0; i < 5; ++i) {
    float t = x[threadIdx.x + 256 * i];
    v[i] = t; s += t; s2 += t * t;
  }
#pragma unroll
  for (int off = 1; off < 64; off <<= 1) {
    s  += __shfl_xor(s,  off, 64);
    s2 += __shfl_xor(s2, off, 64);
  }
  __shared__ float red[8];
  const int wave = threadIdx.x >> 6, lane = threadIdx.x & 63;
  if (lane == 0) { red[wave] = s; red[wave + 4] = s2; }
  __syncthreads();
  s  = red[0] + red[1] + red[2] + red[3];
  s2 = red[4] + red[5] + red[6] + red[7];
  const float mu  = s / HIDn;
  const float var = s2 / HIDn - mu * mu;
  const float rs  = rsqrtf(var + 1e-5f);
#pragma unroll
  for (int i = 0; i < 5; ++i) {
    const int c = threadIdx.x + 256 * i;
    out[(size_t)row * HIDn + c] = (v[i] - mu) * rs * w[c] + b[c];
  }
}

// ---------------------------------------------------------------------------
// NT GEMM: C[m,n] = act((sum_k A[m,k]*W[n,k] + bias[n])*scale + resid[m,n])
// 128x128 tile, 4 waves of 64x64, BK=32, bf16 MFMA 16x16x32, fp32 in/out.
// ---------------------------------------------------------------------------
template<int GELU>
__global__ __launch_bounds__(256) void gemm_nt(
    const float* __restrict__ A, const float* __restrict__ W,
    const float* __restrict__ bias, const float* __restrict__ resid,
    float* __restrict__ Cout, int M, int N, int K, float scale)
{
  __shared__ __align__(16) short As[128][40];   // pad 32->40: row stride 80B
  __shared__ __align__(16) short Bs[128][40];
  const int tid  = threadIdx.x;
  const int lane = tid & 63;
  const int wave = tid >> 6;
  const int wr = wave >> 1, wc = wave & 1;
  const int m0 = blockIdx.x * 128, n0 = blockIdx.y * 128;
  const int lrow = lane & 15;
  const int koff = (lane >> 4) * 8;

  f32x4 acc[4][4];
#pragma unroll
  for (int mi = 0; mi < 4; ++mi)
#pragma unroll
    for (int ni = 0; ni < 4; ++ni)
      acc[mi][ni] = (f32x4){0.f, 0.f, 0.f, 0.f};

  for (int k0 = 0; k0 < K; k0 += 32) {
    // stage A,B tiles: 128x32 f32 each = 1024 float4 each, 4 per thread
#pragma unroll
    for (int i = 0; i < 4; ++i) {
      const int c   = tid + 256 * i;
      const int row = c >> 3;
      const int col = (c & 7) * 4;
      const float4 va = *reinterpret_cast<const float4*>(&A[(size_t)(m0 + row) * K + k0 + col]);
      const float4 vb = *reinterpret_cast<const float4*>(&W[(size_t)(n0 + row) * K + k0 + col]);
      *reinterpret_cast<short4*>(&As[row][col]) =
          make_short4(f2bf(va.x), f2bf(va.y), f2bf(va.z), f2bf(va.w));
      *reinterpret_cast<short4*>(&Bs[row][col]) =
          make_short4(f2bf(vb.x), f2bf(vb.y), f2bf(vb.z), f2bf(vb.w));
    }
    __syncthreads();
    bf16x8 af[4], bfr[4];
#pragma unroll
    for (int mi = 0; mi < 4; ++mi)
      af[mi] = *reinterpret_cast<const bf16x8*>(&As[wr * 64 + mi * 16 + lrow][koff]);
#pragma unroll
    for (int ni = 0; ni < 4; ++ni)
      bfr[ni] = *reinterpret_cast<const bf16x8*>(&Bs[wc * 64 + ni * 16 + lrow][koff]);
#pragma unroll
    for (int mi = 0; mi < 4; ++mi)
#pragma unroll
      for (int ni = 0; ni < 4; ++ni)
        acc[mi][ni] = __builtin_amdgcn_mfma_f32_16x16x32_bf16(af[mi], bfr[ni], acc[mi][ni], 0, 0, 0);
    __syncthreads();
  }

  // epilogue: C/D layout col=lane&15, row=(lane>>4)*4+reg
  const int cn = lane & 15;
  const int rb = (lane >> 4) * 4;
#pragma unroll
  for (int mi = 0; mi < 4; ++mi)
#pragma unroll
    for (int ni = 0; ni < 4; ++ni)
#pragma unroll
      for (int j = 0; j < 4; ++j) {
        const int row = m0 + wr * 64 + mi * 16 + rb + j;
        const int col = n0 + wc * 64 + ni * 16 + cn;
        float t = (acc[mi][ni][j] + bias[col]) * scale;
        if (resid) t += resid[(size_t)row * N + col];
        if (GELU)  t = 0.5f * t * (1.f + erff(t * 0.70710678118654752f));
        Cout[(size_t)row * N + col] = t;
      }
}

// ---------------------------------------------------------------------------
// Fused attention (fp32 SIMT, online softmax).
// Block = 256 threads = 32 query rows x 8 lanes. 64-key chunks.
// Keys 0..Cp-1 come from Kp/Vp ((B,H,Cp,64) layout); keys Cp.. from
// Kn/Vn ((B*Q, HID) layout at head h). mask optional (B,1,Q,KT).
// ---------------------------------------------------------------------------
template<bool HASMASK>
__global__ __launch_bounds__(256) void attn_k(
    const float* __restrict__ Qb, const float* __restrict__ Kp,
    const float* __restrict__ Vp, const float* __restrict__ Kn,
    const float* __restrict__ Vn, const float* __restrict__ mask,
    float* __restrict__ Ob, int Cp, int KT)
{
  const int qt = blockIdx.x, h = blockIdx.y, b = blockIdx.z;
  const int tid = threadIdx.x;
  const int ty = tid >> 3;       // 0..31 query row
  const int tx = tid & 7;        // 0..7
  const int q0 = qt * 32;

  __shared__ float q_s[32][65];
  __shared__ float k_s[64][65];
  __shared__ float v_s[64][65];
  __shared__ float p_s[32][65];

  for (int i = tid; i < 32 * 64; i += 256) {
    const int r = i >> 6, d = i & 63;
    q_s[r][d] = Qb[(size_t)(b * Qn + q0 + r) * HIDn + h * 64 + d];
  }

  float mrun = -1e30f, lrun = 0.f;
  float o[8] = {0.f, 0.f, 0.f, 0.f, 0.f, 0.f, 0.f, 0.f};
  __syncthreads();

  for (int c0 = 0; c0 < KT; c0 += 64) {
    // stage K/V chunk
    for (int i = tid; i < 64 * 64; i += 256) {
      const int r = i >> 6, d = i & 63;
      const int kk = c0 + r;
      float kv = 0.f, vv = 0.f;
      if (kk < KT) {
        if (kk < Cp) {
          const size_t off = (((size_t)b * Hn + h) * Cp + kk) * 64 + d;
          kv = Kp[off]; vv = Vp[off];
        } else {
          const size_t off = (size_t)(b * Qn + (kk - Cp)) * HIDn + h * 64 + d;
          kv = Kn[off]; vv = Vn[off];
        }
      }
      k_s[r][d] = kv; v_s[r][d] = vv;
    }
    __syncthreads();

    // scores: 8 keys per thread
    float sc[8] = {0.f, 0.f, 0.f, 0.f, 0.f, 0.f, 0.f, 0.f};
    for (int d = 0; d < 64; ++d) {
      const float qv = q_s[ty][d];
#pragma unroll
      for (int j = 0; j < 8; ++j) sc[j] += qv * k_s[tx * 8 + j][d];
    }
    float cmax = -1e30f;
#pragma unroll
    for (int j = 0; j < 8; ++j) {
      const int gk = c0 + tx * 8 + j;
      if (HASMASK) sc[j] += mask[((size_t)b * Qn + (q0 + ty)) * KT + gk];
      if (gk >= KT) sc[j] = -1e30f;
      cmax = fmaxf(cmax, sc[j]);
    }
#pragma unroll
    for (int off = 1; off < 8; off <<= 1) cmax = fmaxf(cmax, __shfl_xor(cmax, off, 64));
    const float mnew  = fmaxf(mrun, cmax);
    const float alpha = __expf(mrun - mnew);
    float csum = 0.f;
#pragma unroll
    for (int j = 0; j < 8; ++j) { const float p = __expf(sc[j] - mnew); sc[j] = p; csum += p; }
#pragma unroll
    for (int off = 1; off < 8; off <<= 1) csum += __shfl_xor(csum, off, 64);
    lrun = lrun * alpha + csum;
    mrun = mnew;
#pragma unroll
    for (int j = 0; j < 8; ++j) o[j] *= alpha;
#pragma unroll
    for (int j = 0; j < 8; ++j) p_s[ty][tx * 8 + j] = sc[j];
    __syncthreads();

    // PV accumulate: o[d] for d = tx*8..tx*8+7
    for (int kk = 0; kk < 64; ++kk) {
      const float p = p_s[ty][kk];
#pragma unroll
      for (int j = 0; j < 8; ++j) o[j] += p * v_s[kk][tx * 8 + j];
    }
    __syncthreads();
  }

  const float invl = 1.f / lrun;
#pragma unroll
  for (int j = 0; j < 8; ++j)
    Ob[(size_t)(b * Qn + q0 + ty) * HIDn + h * 64 + tx * 8 + j] = o[j] * invl;
}

// ---------------------------------------------------------------------------
// present_key/value = new K/V rows (Q-C)..Q-1 reshaped to (B,H,C,D)
// ---------------------------------------------------------------------------
__global__ __launch_bounds__(256) void copy_present_k(
    const float* __restrict__ kn, const float* __restrict__ vn,
    float* __restrict__ outk, float* __restrict__ outv)
{
  const int idx = blockIdx.x * 256 + threadIdx.x;     // over B*H*C*16 float4s
  if (idx >= Bc * Hn * Cn * 16) return;
  const int d4 = idx & 15;
  int t = idx >> 4;
  const int c = t % Cn; t /= Cn;
  const int h = t % Hn;
  const int b = t / Hn;
  const size_t src = (size_t)(b * Qn + (Qn - Cn) + c) * HIDn + h * 64 + d4 * 4;
  const size_t dst = (((size_t)b * Hn + h) * Cn + c) * 64 + d4 * 4;
  *reinterpret_cast<float4*>(&outk[dst]) = *reinterpret_cast<const float4*>(&kn[src]);
  *reinterpret_cast<float4*>(&outv[dst]) = *reinterpret_cast<const float4*>(&vn[src]);
}

// ---------------------------------------------------------------------------
extern "C" void kernel_launch(void* const* d_in, const int* in_sizes, int n_in,
                              void* d_out, int out_size, void* d_ws, size_t ws_size,
                              hipStream_t stream)
{
  const float* hidden  = (const float*)d_in[0];
  const float* mask    = (const float*)d_in[1];
  const float* past_k  = (const float*)d_in[2];
  const float* past_v  = (const float*)d_in[3];
  const float* cross_k = (const float*)d_in[4];
  const float* cross_v = (const float*)d_in[5];
  const float* q_w  = (const float*)d_in[6];  const float* q_b  = (const float*)d_in[7];
  const float* k_w  = (const float*)d_in[8];  const float* k_b  = (const float*)d_in[9];
  const float* v_w  = (const float*)d_in[10]; const float* v_b  = (const float*)d_in[11];
  const float* o_w  = (const float*)d_in[12]; const float* o_b  = (const float*)d_in[13];
  const float* cq_w = (const float*)d_in[14]; const float* cq_b = (const float*)d_in[15];
  const float* co_w = (const float*)d_in[16]; const float* co_b = (const float*)d_in[17];
  const float* up_w = (const float*)d_in[18]; const float* up_b = (const float*)d_in[19];
  const float* dn_w = (const float*)d_in[20]; const float* dn_b = (const float*)d_in[21];
  const float* ln1w = (const float*)d_in[22]; const float* ln1b = (const float*)d_in[23];
  const float* ln2w = (const float*)d_in[24]; const float* ln2b = (const float*)d_in[25];
  const float* ln3w = (const float*)d_in[26]; const float* ln3b = (const float*)d_in[27];

  float* s0 = (float*)d_ws;        // x1 -> cattn -> x3
  float* s1 = s0 + S1;             // q  -> h1 (in-place residual chain)
  float* s2 = s1 + S1;             // k  -> x2 -> h2
  float* s3 = s2 + S1;             // v  -> cq
  float* up = s3 + S1;             // up projection (BQ x I)

  float* out_h  = (float*)d_out;
  float* out_pk = out_h + S1;
  float* out_pv = out_pk + (Bc * Hn * Cn * Dn);

  const dim3 blk(256);
  const dim3 gsmall(16, 10);       // 2048/128 x 1280/128
  const dim3 gup(16, 40);          // 2048/128 x 5120/128
  const dim3 gattn(Qn / 32, Hn, Bc);

  // x1 = LN1(hidden)
  layernorm_k<<<BQ, blk, 0, stream>>>(hidden, ln1w, ln1b, s0);
  // q = (x1 Wq^T + bq)*scale ; k,v
  gemm_nt<0><<<gsmall, blk, 0, stream>>>(s0, q_w, q_b, nullptr, s1, BQ, HIDn, HIDn, 0.125f);
  gemm_nt<0><<<gsmall, blk, 0, stream>>>(s0, k_w, k_b, nullptr, s2, BQ, HIDn, HIDn, 1.f);
  gemm_nt<0><<<gsmall, blk, 0, stream>>>(s0, v_w, v_b, nullptr, s3, BQ, HIDn, HIDn, 1.f);
  // present kv (new rows 64..255)
  copy_present_k<<<(Bc * Hn * Cn * 16 + 255) / 256, blk, 0, stream>>>(s2, s3, out_pk, out_pv);
  // self attention -> ctx (s0)
  attn_k<true><<<gattn, blk, 0, stream>>>(s1, past_k, past_v, s2, s3, mask, s0, Cn, KSELF);
  // h1 = hidden + ctx Wo^T + bo   (s1)
  gemm_nt<0><<<gsmall, blk, 0, stream>>>(s0, o_w, o_b, hidden, s1, BQ, HIDn, HIDn, 1.f);
  // x2 = LN2(h1) (s2)
  layernorm_k<<<BQ, blk, 0, stream>>>(s1, ln2w, ln2b, s2);
  // cq = (x2 Wcq^T + b)*scale (s3)
  gemm_nt<0><<<gsmall, blk, 0, stream>>>(s2, cq_w, cq_b, nullptr, s3, BQ, HIDn, HIDn, 0.125f);
  // cross attention -> cattn (s0)
  attn_k<false><<<gattn, blk, 0, stream>>>(s3, cross_k, cross_v, nullptr, nullptr, nullptr, s0, En, En);
  // h2 = h1 + cattn Wco^T + b (s2)
  gemm_nt<0><<<gsmall, blk, 0, stream>>>(s0, co_w, co_b, s1, s2, BQ, HIDn, HIDn, 1.f);
  // x3 = LN3(h2) (s0)
  layernorm_k<<<BQ, blk, 0, stream>>>(s2, ln3w, ln3b, s0);
  // up = gelu(x3 Wup^T + b)
  gemm_nt<1><<<gup, blk, 0, stream>>>(s0, up_w, up_b, nullptr, up, BQ, In, HIDn, 1.f);
  // out_h = h2 + up Wdn^T + b
  gemm_nt<0><<<gsmall, blk, 0, stream>>>(up, dn_w, dn_b, s2, out_h, BQ, HIDn, In, 1.f);
}

// Round 2
// 962.406 us; speedup vs baseline: 2.0190x; 2.0190x over previous
//
#include <hip/hip_runtime.h>
#include <math.h>

// Problem constants
#define Bc   8
#define Qn   256
#define Cn   192
#define Hn   20
#define Dn   64
#define En   1500
#define In   5120
#define HIDn 1280
#define BQ   2048            // B*Q rows
#define KSELF 448            // Q + C
#define S1   (BQ*HIDn)       // 2,621,440 floats
#define SI   ((size_t)BQ*In) // 10,485,760 floats
// ws requirement: (4*S1 + SI)*4 bytes = 83.9 MB

typedef __attribute__((ext_vector_type(8))) short bf16x8;
typedef __attribute__((ext_vector_type(4))) float f32x4;

__device__ __forceinline__ short f2bf(float f) {
  union { float f; unsigned u; } x; x.f = f;
  unsigned r = x.u + 0x7fffu + ((x.u >> 16) & 1u);   // round-to-nearest-even
  return (short)(r >> 16);
}

// ---------------------------------------------------------------------------
// LayerNorm: one 256-thread block per row of 1280
// ---------------------------------------------------------------------------
__global__ __launch_bounds__(256) void layernorm_k(
    const float* __restrict__ in, const float* __restrict__ w,
    const float* __restrict__ b, float* __restrict__ out)
{
  const int row = blockIdx.x;
  const float* x = in + (size_t)row * HIDn;
  float v[5], s = 0.f, s2 = 0.f;
#pragma unroll
  for (int i = 0; i < 5; ++i) {
    float t = x[threadIdx.x + 256 * i];
    v[i] = t; s += t; s2 += t * t;
  }
#pragma unroll
  for (int off = 1; off < 64; off <<= 1) {
    s  += __shfl_xor(s,  off, 64);
    s2 += __shfl_xor(s2, off, 64);
  }
  __shared__ float red[8];
  const int wave = threadIdx.x >> 6, lane = threadIdx.x & 63;
  if (lane == 0) { red[wave] = s; red[wave + 4] = s2; }
  __syncthreads();
  s  = red[0] + red[1] + red[2] + red[3];
  s2 = red[4] + red[5] + red[6] + red[7];
  const float mu  = s / HIDn;
  const float var = s2 / HIDn - mu * mu;
  const float rs  = rsqrtf(var + 1e-5f);
#pragma unroll
  for (int i = 0; i < 5; ++i) {
    const int c = threadIdx.x + 256 * i;
    out[(size_t)row * HIDn + c] = (v[i] - mu) * rs * w[c] + b[c];
  }
}

// ---------------------------------------------------------------------------
// NT GEMM: C[m,n] = act((sum_k A[m,k]*W[n,k] + bias[n])*scale + resid[m,n])
// 128x128 tile, 4 waves of 64x64, BK=32, bf16 MFMA 16x16x32, fp32 in/out.
// ---------------------------------------------------------------------------
template<int GELU>
__global__ __launch_bounds__(256) void gemm_nt(
    const float* __restrict__ A, const float* __restrict__ W,
    const float* __restrict__ bias, const float* __restrict__ resid,
    float* __restrict__ Cout, int M, int N, int K, float scale)
{
  __shared__ __align__(16) short As[128][40];   // pad 32->40: row stride 80B
  __shared__ __align__(16) short Bs[128][40];
  const int tid  = threadIdx.x;
  const int lane = tid & 63;
  const int wave = tid >> 6;
  const int wr = wave >> 1, wc = wave & 1;
  const int m0 = blockIdx.x * 128, n0 = blockIdx.y * 128;
  const int lrow = lane & 15;
  const int koff = (lane >> 4) * 8;

  f32x4 acc[4][4];
#pragma unroll
  for (int mi = 0; mi < 4; ++mi)
#pragma unroll
    for (int ni = 0; ni < 4; ++ni)
      acc[mi][ni] = (f32x4){0.f, 0.f, 0.f, 0.f};

  for (int k0 = 0; k0 < K; k0 += 32) {
    // stage A,B tiles: 128x32 f32 each = 1024 float4 each, 4 per thread
#pragma unroll
    for (int i = 0; i < 4; ++i) {
      const int c   = tid + 256 * i;
      const int row = c >> 3;
      const int col = (c & 7) * 4;
      const float4 va = *reinterpret_cast<const float4*>(&A[(size_t)(m0 + row) * K + k0 + col]);
      const float4 vb = *reinterpret_cast<const float4*>(&W[(size_t)(n0 + row) * K + k0 + col]);
      *reinterpret_cast<short4*>(&As[row][col]) =
          make_short4(f2bf(va.x), f2bf(va.y), f2bf(va.z), f2bf(va.w));
      *reinterpret_cast<short4*>(&Bs[row][col]) =
          make_short4(f2bf(vb.x), f2bf(vb.y), f2bf(vb.z), f2bf(vb.w));
    }
    __syncthreads();
    bf16x8 af[4], bfr[4];
#pragma unroll
    for (int mi = 0; mi < 4; ++mi)
      af[mi] = *reinterpret_cast<const bf16x8*>(&As[wr * 64 + mi * 16 + lrow][koff]);
#pragma unroll
    for (int ni = 0; ni < 4; ++ni)
      bfr[ni] = *reinterpret_cast<const bf16x8*>(&Bs[wc * 64 + ni * 16 + lrow][koff]);
#pragma unroll
    for (int mi = 0; mi < 4; ++mi)
#pragma unroll
      for (int ni = 0; ni < 4; ++ni)
        acc[mi][ni] = __builtin_amdgcn_mfma_f32_16x16x32_bf16(af[mi], bfr[ni], acc[mi][ni], 0, 0, 0);
    __syncthreads();
  }

  // epilogue: C/D layout col=lane&15, row=(lane>>4)*4+reg
  const int cn = lane & 15;
  const int rb = (lane >> 4) * 4;
#pragma unroll
  for (int mi = 0; mi < 4; ++mi)
#pragma unroll
    for (int ni = 0; ni < 4; ++ni)
#pragma unroll
      for (int j = 0; j < 4; ++j) {
        const int row = m0 + wr * 64 + mi * 16 + rb + j;
        const int col = n0 + wc * 64 + ni * 16 + cn;
        float t = (acc[mi][ni][j] + bias[col]) * scale;
        if (resid) t += resid[(size_t)row * N + col];
        if (GELU)  t = 0.5f * t * (1.f + erff(t * 0.70710678118654752f));
        Cout[(size_t)row * N + col] = t;
      }
}

// ---------------------------------------------------------------------------
// MFMA flash attention.
// Block = 256 threads = 4 waves; each wave owns 16 query rows of a 64-row
// Q tile. Keys in 64-chunks. Keys 0..Cp-1 from Kp/Vp ((B,H,Cp,64)); keys
// Cp.. from Kn/Vn ((B*Q, HID) at head h). mask optional (B,1,Q,KT).
//
// MFMA 16x16x32 bf16 fragment mappings (verified by the GEMM above):
//   A/B: lane index l&15 = row/col, k = (l>>4)*8 .. +7
//   C/D: col = l&15, row = (l>>4)*4 + reg
// ---------------------------------------------------------------------------
template<bool HASMASK>
__global__ __launch_bounds__(256) void attn_mfma(
    const float* __restrict__ Qb, const float* __restrict__ Kp,
    const float* __restrict__ Vp, const float* __restrict__ Kn,
    const float* __restrict__ Vn, const float* __restrict__ mask,
    float* __restrict__ Ob, int Cp, int KT)
{
  const int qt = blockIdx.x, h = blockIdx.y, b = blockIdx.z;
  const int tid = threadIdx.x, lane = tid & 63, wave = tid >> 6;
  const int q0 = qt * 64;
  const int cn = lane & 15;      // fragment row/col index
  const int hg = lane >> 4;      // quarter-wave group
  const int rb = hg * 4;         // C/D row base

  __shared__ __align__(16) short k_s[64][72];      // [key][d]
  __shared__ __align__(16) short vt_s[64][72];     // [d][key-swizzled]
  __shared__ __align__(16) short p_s[4][16][72];   // per-wave P [qrow][key]

  // Q fragments: rows q0+wave*16+cn, k = kk*32 + hg*8 .. +7  (Q pre-scaled)
  bf16x8 aq[2];
  {
    const float* qrow = Qb + (size_t)(b * Qn + q0 + wave * 16 + cn) * HIDn + h * 64;
#pragma unroll
    for (int kk = 0; kk < 2; ++kk) {
      const float4 x = *reinterpret_cast<const float4*>(qrow + kk * 32 + hg * 8);
      const float4 y = *reinterpret_cast<const float4*>(qrow + kk * 32 + hg * 8 + 4);
      bf16x8 t;
      t[0] = f2bf(x.x); t[1] = f2bf(x.y); t[2] = f2bf(x.z); t[3] = f2bf(x.w);
      t[4] = f2bf(y.x); t[5] = f2bf(y.y); t[6] = f2bf(y.z); t[7] = f2bf(y.w);
      aq[kk] = t;
    }
  }

  float mrun[4] = {-1e30f, -1e30f, -1e30f, -1e30f};
  float lrun[4] = {0.f, 0.f, 0.f, 0.f};
  f32x4 oacc[4];
#pragma unroll
  for (int t = 0; t < 4; ++t) oacc[t] = (f32x4){0.f, 0.f, 0.f, 0.f};

  const int nchunk = (KT + 63) >> 6;
  for (int ci = 0; ci < nchunk; ++ci) {
    const int c0 = ci * 64;
    // ---- stage K (row-major) and V (transposed + swizzled) as bf16 ----
    for (int i = tid; i < 64 * 16; i += 256) {
      const int key = i >> 4, d4 = (i & 15) * 4;
      const int gk = c0 + key;
      float4 kv = {0.f, 0.f, 0.f, 0.f}, vv = {0.f, 0.f, 0.f, 0.f};
      if (gk < KT) {
        if (gk < Cp) {
          const size_t off = (((size_t)b * Hn + h) * (size_t)Cp + gk) * 64 + d4;
          kv = *reinterpret_cast<const float4*>(Kp + off);
          vv = *reinterpret_cast<const float4*>(Vp + off);
        } else {
          const size_t off = (size_t)(b * Qn + (gk - Cp)) * HIDn + h * 64 + d4;
          kv = *reinterpret_cast<const float4*>(Kn + off);
          vv = *reinterpret_cast<const float4*>(Vn + off);
        }
      }
      *reinterpret_cast<short4*>(&k_s[key][d4]) =
          make_short4(f2bf(kv.x), f2bf(kv.y), f2bf(kv.z), f2bf(kv.w));
      const int g = key >> 3, o = key & 7;
      const float vvj[4] = {vv.x, vv.y, vv.z, vv.w};
#pragma unroll
      for (int j = 0; j < 4; ++j) {
        const int d = d4 + j;
        vt_s[d][((g ^ ((d >> 3) & 7)) << 3) | o] = f2bf(vvj[j]);
      }
    }
    __syncthreads();

    // ---- QK^T: S[16q x 64key] per wave ----
    f32x4 sacc[4];
#pragma unroll
    for (int t = 0; t < 4; ++t) sacc[t] = (f32x4){0.f, 0.f, 0.f, 0.f};
#pragma unroll
    for (int t = 0; t < 4; ++t)
#pragma unroll
      for (int kk = 0; kk < 2; ++kk) {
        const bf16x8 bk = *reinterpret_cast<const bf16x8*>(&k_s[t * 16 + cn][kk * 32 + hg * 8]);
        sacc[t] = __builtin_amdgcn_mfma_f32_16x16x32_bf16(aq[kk], bk, sacc[t], 0, 0, 0);
      }

    // ---- mask + tail ----
    float sc[4][4];
#pragma unroll
    for (int t = 0; t < 4; ++t) {
      const int key = c0 + t * 16 + cn;
      const bool valid = key < KT;
#pragma unroll
      for (int j = 0; j < 4; ++j) {
        float v = sacc[t][j];
        if (HASMASK && valid)
          v += mask[((size_t)(b * Qn) + q0 + wave * 16 + rb + j) * KT + key];
        sc[t][j] = valid ? v : -1e30f;
      }
    }

    // ---- online softmax (row r = rb+j lives in the 16 lanes sharing hg) ----
#pragma unroll
    for (int j = 0; j < 4; ++j) {
      float mx = fmaxf(fmaxf(sc[0][j], sc[1][j]), fmaxf(sc[2][j], sc[3][j]));
#pragma unroll
      for (int off = 1; off < 16; off <<= 1) mx = fmaxf(mx, __shfl_xor(mx, off, 64));
      const float mnew  = fmaxf(mrun[j], mx);
      const float alpha = __expf(mrun[j] - mnew);
      float ps = 0.f;
#pragma unroll
      for (int t = 0; t < 4; ++t) {
        const float p = __expf(sc[t][j] - mnew);
        sc[t][j] = p; ps += p;
      }
#pragma unroll
      for (int off = 1; off < 16; off <<= 1) ps += __shfl_xor(ps, off, 64);
      lrun[j] = lrun[j] * alpha + ps;
      mrun[j] = mnew;
#pragma unroll
      for (int t = 0; t < 4; ++t) oacc[t][j] *= alpha;
    }

    // ---- P -> LDS (per-wave slice; same-wave RAW, no barrier needed) ----
#pragma unroll
    for (int t = 0; t < 4; ++t)
#pragma unroll
      for (int j = 0; j < 4; ++j)
        p_s[wave][rb + j][t * 16 + cn] = f2bf(sc[t][j]);

    // ---- PV: O[16q x 64d] += P @ V ----
    const bf16x8 ap0 = *reinterpret_cast<const bf16x8*>(&p_s[wave][cn][hg * 8]);
    const bf16x8 ap1 = *reinterpret_cast<const bf16x8*>(&p_s[wave][cn][32 + hg * 8]);
#pragma unroll
    for (int t = 0; t < 4; ++t) {
      const int d  = t * 16 + cn;
      const int fd = (d >> 3) & 7;
      const bf16x8 bv0 = *reinterpret_cast<const bf16x8*>(&vt_s[d][((hg)     ^ fd) << 3]);
      const bf16x8 bv1 = *reinterpret_cast<const bf16x8*>(&vt_s[d][((4 + hg) ^ fd) << 3]);
      oacc[t] = __builtin_amdgcn_mfma_f32_16x16x32_bf16(ap0, bv0, oacc[t], 0, 0, 0);
      oacc[t] = __builtin_amdgcn_mfma_f32_16x16x32_bf16(ap1, bv1, oacc[t], 0, 0, 0);
    }
    __syncthreads();
  }

  // ---- epilogue ----
#pragma unroll
  for (int t = 0; t < 4; ++t)
#pragma unroll
    for (int j = 0; j < 4; ++j)
      Ob[(size_t)(b * Qn + q0 + wave * 16 + rb + j) * HIDn + h * 64 + t * 16 + cn] =
          oacc[t][j] / lrun[j];
}

// ---------------------------------------------------------------------------
// present_key/value = new K/V rows (Q-C)..Q-1 reshaped to (B,H,C,D)
// ---------------------------------------------------------------------------
__global__ __launch_bounds__(256) void copy_present_k(
    const float* __restrict__ kn, const float* __restrict__ vn,
    float* __restrict__ outk, float* __restrict__ outv)
{
  const int idx = blockIdx.x * 256 + threadIdx.x;     // over B*H*C*16 float4s
  if (idx >= Bc * Hn * Cn * 16) return;
  const int d4 = idx & 15;
  int t = idx >> 4;
  const int c = t % Cn; t /= Cn;
  const int h = t % Hn;
  const int b = t / Hn;
  const size_t src = (size_t)(b * Qn + (Qn - Cn) + c) * HIDn + h * 64 + d4 * 4;
  const size_t dst = (((size_t)b * Hn + h) * Cn + c) * 64 + d4 * 4;
  *reinterpret_cast<float4*>(&outk[dst]) = *reinterpret_cast<const float4*>(&kn[src]);
  *reinterpret_cast<float4*>(&outv[dst]) = *reinterpret_cast<const float4*>(&vn[src]);
}

// ---------------------------------------------------------------------------
extern "C" void kernel_launch(void* const* d_in, const int* in_sizes, int n_in,
                              void* d_out, int out_size, void* d_ws, size_t ws_size,
                              hipStream_t stream)
{
  const float* hidden  = (const float*)d_in[0];
  const float* mask    = (const float*)d_in[1];
  const float* past_k  = (const float*)d_in[2];
  const float* past_v  = (const float*)d_in[3];
  const float* cross_k = (const float*)d_in[4];
  const float* cross_v = (const float*)d_in[5];
  const float* q_w  = (const float*)d_in[6];  const float* q_b  = (const float*)d_in[7];
  const float* k_w  = (const float*)d_in[8];  const float* k_b  = (const float*)d_in[9];
  const float* v_w  = (const float*)d_in[10]; const float* v_b  = (const float*)d_in[11];
  const float* o_w  = (const float*)d_in[12]; const float* o_b  = (const float*)d_in[13];
  const float* cq_w = (const float*)d_in[14]; const float* cq_b = (const float*)d_in[15];
  const float* co_w = (const float*)d_in[16]; const float* co_b = (const float*)d_in[17];
  const float* up_w = (const float*)d_in[18]; const float* up_b = (const float*)d_in[19];
  const float* dn_w = (const float*)d_in[20]; const float* dn_b = (const float*)d_in[21];
  const float* ln1w = (const float*)d_in[22]; const float* ln1b = (const float*)d_in[23];
  const float* ln2w = (const float*)d_in[24]; const float* ln2b = (const float*)d_in[25];
  const float* ln3w = (const float*)d_in[26]; const float* ln3b = (const float*)d_in[27];

  float* s0 = (float*)d_ws;        // x1 -> cattn -> x3
  float* s1 = s0 + S1;             // q  -> h1
  float* s2 = s1 + S1;             // k  -> x2 -> h2
  float* s3 = s2 + S1;             // v  -> cq
  float* up = s3 + S1;             // up projection (BQ x I)

  float* out_h  = (float*)d_out;
  float* out_pk = out_h + S1;
  float* out_pv = out_pk + (Bc * Hn * Cn * Dn);

  const dim3 blk(256);
  const dim3 gsmall(16, 10);       // 2048/128 x 1280/128
  const dim3 gup(16, 40);          // 2048/128 x 5120/128
  const dim3 gattn(Qn / 64, Hn, Bc);

  // x1 = LN1(hidden)
  layernorm_k<<<BQ, blk, 0, stream>>>(hidden, ln1w, ln1b, s0);
  // q = (x1 Wq^T + bq)*scale ; k,v
  gemm_nt<0><<<gsmall, blk, 0, stream>>>(s0, q_w, q_b, nullptr, s1, BQ, HIDn, HIDn, 0.125f);
  gemm_nt<0><<<gsmall, blk, 0, stream>>>(s0, k_w, k_b, nullptr, s2, BQ, HIDn, HIDn, 1.f);
  gemm_nt<0><<<gsmall, blk, 0, stream>>>(s0, v_w, v_b, nullptr, s3, BQ, HIDn, HIDn, 1.f);
  // present kv (new rows 64..255)
  copy_present_k<<<(Bc * Hn * Cn * 16 + 255) / 256, blk, 0, stream>>>(s2, s3, out_pk, out_pv);
  // self attention -> ctx (s0)
  attn_mfma<true><<<gattn, blk, 0, stream>>>(s1, past_k, past_v, s2, s3, mask, s0, Cn, KSELF);
  // h1 = hidden + ctx Wo^T + bo   (s1)
  gemm_nt<0><<<gsmall, blk, 0, stream>>>(s0, o_w, o_b, hidden, s1, BQ, HIDn, HIDn, 1.f);
  // x2 = LN2(h1) (s2)
  layernorm_k<<<BQ, blk, 0, stream>>>(s1, ln2w, ln2b, s2);
  // cq = (x2 Wcq^T + b)*scale (s3)
  gemm_nt<0><<<gsmall, blk, 0, stream>>>(s2, cq_w, cq_b, nullptr, s3, BQ, HIDn, HIDn, 0.125f);
  // cross attention -> cattn (s0)
  attn_mfma<false><<<gattn, blk, 0, stream>>>(s3, cross_k, cross_v, nullptr, nullptr, nullptr, s0, En, En);
  // h2 = h1 + cattn Wco^T + b (s2)
  gemm_nt<0><<<gsmall, blk, 0, stream>>>(s0, co_w, co_b, s1, s2, BQ, HIDn, HIDn, 1.f);
  // x3 = LN3(h2) (s0)
  layernorm_k<<<BQ, blk, 0, stream>>>(s2, ln3w, ln3b, s0);
  // up = gelu(x3 Wup^T + b)
  gemm_nt<1><<<gup, blk, 0, stream>>>(s0, up_w, up_b, nullptr, up, BQ, In, HIDn, 1.f);
  // out_h = h2 + up Wdn^T + b
  gemm_nt<0><<<gsmall, blk, 0, stream>>>(up, dn_w, dn_b, s2, out_h, BQ, HIDn, In, 1.f);
}

// Round 3
// 525.308 us; speedup vs baseline: 3.6990x; 1.8321x over previous
//
#include <hip/hip_runtime.h>
#include <math.h>

// Problem constants
#define Bc   8
#define Qn   256
#define Cn   192
#define Hn   20
#define Dn   64
#define En   1500
#define In   5120
#define HIDn 1280
#define BQ   2048            // B*Q rows
#define KSELF 448            // Q + C
#define S1   (BQ*HIDn)       // 2,621,440
#define WSZ  (HIDn*HIDn)     // 1,638,400

typedef __attribute__((ext_vector_type(8))) short bf16x8;
typedef __attribute__((ext_vector_type(4))) float f32x4;

__device__ __forceinline__ short f2bf(float f) {
  union { float f; unsigned u; } x; x.f = f;
  unsigned r = x.u + 0x7fffu + ((x.u >> 16) & 1u);   // RNE
  return (short)(r >> 16);
}
__device__ __forceinline__ float bf2f(short s) {
  union { unsigned u; float f; } x; x.u = ((unsigned)(unsigned short)s) << 16;
  return x.f;
}
__device__ __forceinline__ void gload16(const short* g, short* l) {
  __builtin_amdgcn_global_load_lds(
      (const __attribute__((address_space(1))) void*)g,
      (__attribute__((address_space(3))) void*)l, 16, 0, 0);
}

// ---------------------------------------------------------------------------
// Convert all 8 weight matrices fp32 -> bf16 (blockIdx.y selects matrix)
// ---------------------------------------------------------------------------
__global__ __launch_bounds__(256) void convert_all(
    const float* q, const float* k, const float* v, const float* o,
    const float* cq, const float* co, const float* up, const float* dn,
    short* wq, short* wk, short* wv, short* wo,
    short* wcq, short* wco, short* wup, short* wdn)
{
  const float* src; short* dst; int n;
  switch (blockIdx.y) {
    case 0: src = q;  dst = wq;  n = WSZ; break;
    case 1: src = k;  dst = wk;  n = WSZ; break;
    case 2: src = v;  dst = wv;  n = WSZ; break;
    case 3: src = o;  dst = wo;  n = WSZ; break;
    case 4: src = cq; dst = wcq; n = WSZ; break;
    case 5: src = co; dst = wco; n = WSZ; break;
    case 6: src = up; dst = wup; n = HIDn * In; break;
    default: src = dn; dst = wdn; n = HIDn * In; break;
  }
  const int i = (blockIdx.x * 256 + threadIdx.x) * 8;
  if (i >= n) return;
  const float4 a = *reinterpret_cast<const float4*>(src + i);
  const float4 b = *reinterpret_cast<const float4*>(src + i + 4);
  bf16x8 t;
  t[0] = f2bf(a.x); t[1] = f2bf(a.y); t[2] = f2bf(a.z); t[3] = f2bf(a.w);
  t[4] = f2bf(b.x); t[5] = f2bf(b.y); t[6] = f2bf(b.z); t[7] = f2bf(b.w);
  *reinterpret_cast<bf16x8*>(dst + i) = t;
}

// ---------------------------------------------------------------------------
// LayerNorm: fp32 in, bf16 out. One 256-thread block per row of 1280.
// ---------------------------------------------------------------------------
__global__ __launch_bounds__(256) void layernorm_k(
    const float* __restrict__ in, const float* __restrict__ w,
    const float* __restrict__ b, short* __restrict__ out)
{
  const int row = blockIdx.x;
  const float* x = in + (size_t)row * HIDn;
  float v[5], s = 0.f, s2 = 0.f;
#pragma unroll
  for (int i = 0; i < 5; ++i) {
    float t = x[threadIdx.x + 256 * i];
    v[i] = t; s += t; s2 += t * t;
  }
#pragma unroll
  for (int off = 1; off < 64; off <<= 1) {
    s  += __shfl_xor(s,  off, 64);
    s2 += __shfl_xor(s2, off, 64);
  }
  __shared__ float red[8];
  const int wave = threadIdx.x >> 6, lane = threadIdx.x & 63;
  if (lane == 0) { red[wave] = s; red[wave + 4] = s2; }
  __syncthreads();
  s  = red[0] + red[1] + red[2] + red[3];
  s2 = red[4] + red[5] + red[6] + red[7];
  const float mu  = s / HIDn;
  const float var = s2 / HIDn - mu * mu;
  const float rs  = rsqrtf(var + 1e-5f);
#pragma unroll
  for (int i = 0; i < 5; ++i) {
    const int c = threadIdx.x + 256 * i;
    out[(size_t)row * HIDn + c] = f2bf((v[i] - mu) * rs * w[c] + b[c]);
  }
}

// ---------------------------------------------------------------------------
// NT GEMM, bf16 inputs via global_load_lds, fragment-order LDS, BK=32.
// 4 waves as 2x2; wave computes (BM/2)x(BN/2) via FM x FN 16x16 frags.
// MODE 0: fp32 out = acc + bias + resid
// MODE 1: bf16 out = (acc + bias) * scale
// MODE 2: bf16 out = gelu(acc + bias)
// MODE 3: QKV triple bf16 out; region by n0/1280; q region scaled 0.125
// ---------------------------------------------------------------------------
template<int BM, int BN, int MODE>
__global__ __launch_bounds__(256) void gemm_lds(
    const short* __restrict__ A, const short* __restrict__ W,
    const float* __restrict__ bias, const float* __restrict__ resid,
    void* __restrict__ out0, void* __restrict__ out1, void* __restrict__ out2,
    const float* __restrict__ b1, const float* __restrict__ b2,
    int N, int K, float scale)
{
  constexpr int FM = BM / 32, FN = BN / 32;
  constexpr int NIA = BM / 16, NIB = BN / 16;   // 1KB issues per matrix
  __shared__ __align__(16) short Alds[BM * 32];
  __shared__ __align__(16) short Blds[BN * 32];
  const int tid = threadIdx.x, lane = tid & 63, wave = tid >> 6;
  const int wr = wave >> 1, wc = wave & 1;
  const int m0 = blockIdx.x * BM, n0 = blockIdx.y * BN;
  const int lr = lane & 15;               // fragment row
  const int kc = (lane >> 4) * 8;         // fragment k offset

  f32x4 acc[FM][FN];
#pragma unroll
  for (int mi = 0; mi < FM; ++mi)
#pragma unroll
    for (int ni = 0; ni < FN; ++ni)
      acc[mi][ni] = (f32x4){0.f, 0.f, 0.f, 0.f};

  const int nk = K >> 5;
  for (int kt = 0; kt < nk; ++kt) {
    const int k0 = kt << 5;
#pragma unroll
    for (int j = 0; j < NIA / 4; ++j) {
      const int ia  = wave + 4 * j;
      const int row = (ia / FM) * (BM / 2) + (ia % FM) * 16 + lr;
      gload16(A + (size_t)(m0 + row) * K + k0 + kc, &Alds[ia * 512]);
    }
#pragma unroll
    for (int j = 0; j < NIB / 4; ++j) {
      const int ib  = wave + 4 * j;
      const int row = (ib / FN) * (BN / 2) + (ib % FN) * 16 + lr;
      gload16(W + (size_t)(n0 + row) * K + k0 + kc, &Blds[ib * 512]);
    }
    __syncthreads();
    bf16x8 af[FM], bfv[FN];
#pragma unroll
    for (int mi = 0; mi < FM; ++mi)
      af[mi] = *reinterpret_cast<const bf16x8*>(&Alds[((wr * FM + mi) * 64 + lane) * 8]);
#pragma unroll
    for (int ni = 0; ni < FN; ++ni)
      bfv[ni] = *reinterpret_cast<const bf16x8*>(&Blds[((wc * FN + ni) * 64 + lane) * 8]);
#pragma unroll
    for (int mi = 0; mi < FM; ++mi)
#pragma unroll
      for (int ni = 0; ni < FN; ++ni)
        acc[mi][ni] = __builtin_amdgcn_mfma_f32_16x16x32_bf16(af[mi], bfv[ni], acc[mi][ni], 0, 0, 0);
    __syncthreads();
  }

  // epilogue: C/D col = lane&15, row = (lane>>4)*4 + reg
  const int cn = lane & 15;
  const int rb = (lane >> 4) * 4;
#pragma unroll
  for (int mi = 0; mi < FM; ++mi)
#pragma unroll
    for (int ni = 0; ni < FN; ++ni)
#pragma unroll
      for (int j = 0; j < 4; ++j) {
        const int row = m0 + wr * (BM / 2) + mi * 16 + rb + j;
        const int col = n0 + wc * (BN / 2) + ni * 16 + cn;
        const float a = acc[mi][ni][j];
        if (MODE == 0) {
          ((float*)out0)[(size_t)row * N + col] =
              a + bias[col] + resid[(size_t)row * N + col];
        } else if (MODE == 1) {
          ((short*)out0)[(size_t)row * N + col] = f2bf((a + bias[col]) * scale);
        } else if (MODE == 2) {
          float t = a + bias[col];
          t = 0.5f * t * (1.f + erff(t * 0.70710678118654752f));
          ((short*)out0)[(size_t)row * N + col] = f2bf(t);
        } else {
          const int rg  = n0 / 1280;
          const int cl  = col - rg * 1280;
          short* op     = rg == 0 ? (short*)out0 : rg == 1 ? (short*)out1 : (short*)out2;
          const float* bp = rg == 0 ? bias : rg == 1 ? b1 : b2;
          const float sc  = rg == 0 ? 0.125f : 1.f;
          op[(size_t)row * 1280 + cl] = f2bf((a + bp[cl]) * sc);
        }
      }
}

// ---------------------------------------------------------------------------
// MFMA flash attention. Q/Kn/Vn/out bf16; past K/V fp32.
// Block = 4 waves; each wave owns 16 q-rows of a 64-row Q tile; 64-key chunks.
// ---------------------------------------------------------------------------
template<bool HASMASK>
__global__ __launch_bounds__(256) void attn_mfma(
    const short* __restrict__ Qb, const float* __restrict__ Kp,
    const float* __restrict__ Vp, const short* __restrict__ Kn,
    const short* __restrict__ Vn, const float* __restrict__ mask,
    short* __restrict__ Ob, int Cp, int KT)
{
  const int qt = blockIdx.x, h = blockIdx.y, b = blockIdx.z;
  const int tid = threadIdx.x, lane = tid & 63, wave = tid >> 6;
  const int q0 = qt * 64;
  const int cn = lane & 15;
  const int hg = lane >> 4;
  const int rb = hg * 4;

  __shared__ __align__(16) short k_s[64][72];
  __shared__ __align__(16) short vt_s[64][72];
  __shared__ __align__(16) short p_s[4][16][72];

  bf16x8 aq[2];
  {
    const short* qrow = Qb + (size_t)(b * Qn + q0 + wave * 16 + cn) * HIDn + h * 64;
    aq[0] = *reinterpret_cast<const bf16x8*>(qrow + hg * 8);
    aq[1] = *reinterpret_cast<const bf16x8*>(qrow + 32 + hg * 8);
  }

  float mrun[4] = {-1e30f, -1e30f, -1e30f, -1e30f};
  float lrun[4] = {0.f, 0.f, 0.f, 0.f};
  f32x4 oacc[4];
#pragma unroll
  for (int t = 0; t < 4; ++t) oacc[t] = (f32x4){0.f, 0.f, 0.f, 0.f};

  const int nchunk = (KT + 63) >> 6;
  for (int ci = 0; ci < nchunk; ++ci) {
    const int c0 = ci * 64;
    // stage K row-major + V transposed/swizzled, in 8-elem chunks
    for (int i = tid; i < 64 * 8; i += 256) {
      const int key = i >> 3, d8 = (i & 7) * 8;
      const int gk = c0 + key;
      bf16x8 kv8 = (bf16x8)0, vv8 = (bf16x8)0;
      if (gk < KT) {
        if (gk < Cp) {
          const size_t off = (((size_t)b * Hn + h) * (size_t)Cp + gk) * 64 + d8;
          const float4 ka = *reinterpret_cast<const float4*>(Kp + off);
          const float4 kb = *reinterpret_cast<const float4*>(Kp + off + 4);
          const float4 va = *reinterpret_cast<const float4*>(Vp + off);
          const float4 vb = *reinterpret_cast<const float4*>(Vp + off + 4);
          kv8[0] = f2bf(ka.x); kv8[1] = f2bf(ka.y); kv8[2] = f2bf(ka.z); kv8[3] = f2bf(ka.w);
          kv8[4] = f2bf(kb.x); kv8[5] = f2bf(kb.y); kv8[6] = f2bf(kb.z); kv8[7] = f2bf(kb.w);
          vv8[0] = f2bf(va.x); vv8[1] = f2bf(va.y); vv8[2] = f2bf(va.z); vv8[3] = f2bf(va.w);
          vv8[4] = f2bf(vb.x); vv8[5] = f2bf(vb.y); vv8[6] = f2bf(vb.z); vv8[7] = f2bf(vb.w);
        } else {
          const size_t off = (size_t)(b * Qn + (gk - Cp)) * HIDn + h * 64 + d8;
          kv8 = *reinterpret_cast<const bf16x8*>(Kn + off);
          vv8 = *reinterpret_cast<const bf16x8*>(Vn + off);
        }
      }
      *reinterpret_cast<bf16x8*>(&k_s[key][d8]) = kv8;
      const int g = key >> 3, o = key & 7, f = (d8 >> 3) & 7;
#pragma unroll
      for (int j = 0; j < 8; ++j)
        vt_s[d8 + j][((g ^ f) << 3) | o] = vv8[j];
    }
    __syncthreads();

    // QK^T
    f32x4 sacc[4];
#pragma unroll
    for (int t = 0; t < 4; ++t) sacc[t] = (f32x4){0.f, 0.f, 0.f, 0.f};
#pragma unroll
    for (int t = 0; t < 4; ++t)
#pragma unroll
      for (int kk = 0; kk < 2; ++kk) {
        const bf16x8 bk = *reinterpret_cast<const bf16x8*>(&k_s[t * 16 + cn][kk * 32 + hg * 8]);
        sacc[t] = __builtin_amdgcn_mfma_f32_16x16x32_bf16(aq[kk], bk, sacc[t], 0, 0, 0);
      }

    float sc[4][4];
#pragma unroll
    for (int t = 0; t < 4; ++t) {
      const int key = c0 + t * 16 + cn;
      const bool valid = key < KT;
#pragma unroll
      for (int j = 0; j < 4; ++j) {
        float v = sacc[t][j];
        if (HASMASK && valid)
          v += mask[((size_t)(b * Qn) + q0 + wave * 16 + rb + j) * KT + key];
        sc[t][j] = valid ? v : -1e30f;
      }
    }

    // online softmax
#pragma unroll
    for (int j = 0; j < 4; ++j) {
      float mx = fmaxf(fmaxf(sc[0][j], sc[1][j]), fmaxf(sc[2][j], sc[3][j]));
#pragma unroll
      for (int off = 1; off < 16; off <<= 1) mx = fmaxf(mx, __shfl_xor(mx, off, 64));
      const float mnew  = fmaxf(mrun[j], mx);
      const float alpha = __expf(mrun[j] - mnew);
      float ps = 0.f;
#pragma unroll
      for (int t = 0; t < 4; ++t) {
        const float p = __expf(sc[t][j] - mnew);
        sc[t][j] = p; ps += p;
      }
#pragma unroll
      for (int off = 1; off < 16; off <<= 1) ps += __shfl_xor(ps, off, 64);
      lrun[j] = lrun[j] * alpha + ps;
      mrun[j] = mnew;
#pragma unroll
      for (int t = 0; t < 4; ++t) oacc[t][j] *= alpha;
    }

    // P -> per-wave LDS slice
#pragma unroll
    for (int t = 0; t < 4; ++t)
#pragma unroll
      for (int j = 0; j < 4; ++j)
        p_s[wave][rb + j][t * 16 + cn] = f2bf(sc[t][j]);

    // PV
    const bf16x8 ap0 = *reinterpret_cast<const bf16x8*>(&p_s[wave][cn][hg * 8]);
    const bf16x8 ap1 = *reinterpret_cast<const bf16x8*>(&p_s[wave][cn][32 + hg * 8]);
#pragma unroll
    for (int t = 0; t < 4; ++t) {
      const int d  = t * 16 + cn;
      const int fd = (d >> 3) & 7;
      const bf16x8 bv0 = *reinterpret_cast<const bf16x8*>(&vt_s[d][((hg)     ^ fd) << 3]);
      const bf16x8 bv1 = *reinterpret_cast<const bf16x8*>(&vt_s[d][((4 + hg) ^ fd) << 3]);
      oacc[t] = __builtin_amdgcn_mfma_f32_16x16x32_bf16(ap0, bv0, oacc[t], 0, 0, 0);
      oacc[t] = __builtin_amdgcn_mfma_f32_16x16x32_bf16(ap1, bv1, oacc[t], 0, 0, 0);
    }
    __syncthreads();
  }

#pragma unroll
  for (int t = 0; t < 4; ++t)
#pragma unroll
    for (int j = 0; j < 4; ++j)
      Ob[(size_t)(b * Qn + q0 + wave * 16 + rb + j) * HIDn + h * 64 + t * 16 + cn] =
          f2bf(oacc[t][j] / lrun[j]);
}

// ---------------------------------------------------------------------------
// present_key/value: bf16 new K/V rows (Q-C)..Q-1 -> fp32 (B,H,C,D)
// ---------------------------------------------------------------------------
__global__ __launch_bounds__(256) void copy_present(
    const short* __restrict__ kn, const short* __restrict__ vn,
    float* __restrict__ outk, float* __restrict__ outv)
{
  const int idx = blockIdx.x * 256 + threadIdx.x;      // over B*H*C*8 chunks
  if (idx >= Bc * Hn * Cn * 8) return;
  const int d8 = (idx & 7) * 8;
  int t = idx >> 3;
  const int c = t % Cn; t /= Cn;
  const int h = t % Hn;
  const int b = t / Hn;
  const size_t src = (size_t)(b * Qn + (Qn - Cn) + c) * HIDn + h * 64 + d8;
  const size_t dst = (((size_t)b * Hn + h) * Cn + c) * 64 + d8;
  const bf16x8 kv = *reinterpret_cast<const bf16x8*>(kn + src);
  const bf16x8 vv = *reinterpret_cast<const bf16x8*>(vn + src);
#pragma unroll
  for (int j = 0; j < 8; ++j) {
    outk[dst + j] = bf2f(kv[j]);
    outv[dst + j] = bf2f(vv[j]);
  }
}

// ---------------------------------------------------------------------------
extern "C" void kernel_launch(void* const* d_in, const int* in_sizes, int n_in,
                              void* d_out, int out_size, void* d_ws, size_t ws_size,
                              hipStream_t stream)
{
  const float* hidden  = (const float*)d_in[0];
  const float* mask    = (const float*)d_in[1];
  const float* past_k  = (const float*)d_in[2];
  const float* past_v  = (const float*)d_in[3];
  const float* cross_k = (const float*)d_in[4];
  const float* cross_v = (const float*)d_in[5];
  const float* q_w  = (const float*)d_in[6];  const float* q_b  = (const float*)d_in[7];
  const float* k_w  = (const float*)d_in[8];  const float* k_b  = (const float*)d_in[9];
  const float* v_w  = (const float*)d_in[10]; const float* v_b  = (const float*)d_in[11];
  const float* o_w  = (const float*)d_in[12]; const float* o_b  = (const float*)d_in[13];
  const float* cq_w = (const float*)d_in[14]; const float* cq_b = (const float*)d_in[15];
  const float* co_w = (const float*)d_in[16]; const float* co_b = (const float*)d_in[17];
  const float* up_w = (const float*)d_in[18]; const float* up_b = (const float*)d_in[19];
  const float* dn_w = (const float*)d_in[20]; const float* dn_b = (const float*)d_in[21];
  const float* ln1w = (const float*)d_in[22]; const float* ln1b = (const float*)d_in[23];
  const float* ln2w = (const float*)d_in[24]; const float* ln2b = (const float*)d_in[25];
  const float* ln3w = (const float*)d_in[26]; const float* ln3b = (const float*)d_in[27];

  // workspace layout (bf16 weights, bf16 activations, fp32 residuals)
  short* wq  = (short*)d_ws;                    // qkv weights contiguous
  short* wk  = wq  + (size_t)WSZ;
  short* wv  = wk  + (size_t)WSZ;
  short* wo  = wv  + (size_t)WSZ;
  short* wcq = wo  + (size_t)WSZ;
  short* wco = wcq + (size_t)WSZ;
  short* wup = wco + (size_t)WSZ;
  short* wdn = wup + (size_t)HIDn * In;
  short* xb  = wdn + (size_t)HIDn * In;         // LN outputs (reused x1,x2,x3)
  short* qb  = xb  + (size_t)S1;                // q, reused as cq
  short* kb  = qb  + (size_t)S1;
  short* vb  = kb  + (size_t)S1;
  short* ab  = vb  + (size_t)S1;                // attn outputs
  short* upa = ab  + (size_t)S1;                // gelu(up) activations
  float* h1  = (float*)(upa + (size_t)BQ * In);
  float* h2  = h1 + (size_t)S1;

  float* out_h  = (float*)d_out;
  float* out_pk = out_h + (size_t)S1;
  float* out_pv = out_pk + (size_t)(Bc * Hn * Cn * Dn);

  const dim3 blk(256);
  const dim3 gconv(3200, 8);
  const dim3 gqkv(16, 30);         // 2048/128 x 3840/128
  const dim3 g64(32, 20);          // 2048/64 x 1280/64
  const dim3 gup(16, 40);          // 2048/128 x 5120/128
  const dim3 gattn(Qn / 64, Hn, Bc);

  // weights -> bf16
  convert_all<<<gconv, blk, 0, stream>>>(q_w, k_w, v_w, o_w, cq_w, co_w, up_w, dn_w,
                                         wq, wk, wv, wo, wcq, wco, wup, wdn);
  // x1 = LN1(hidden)
  layernorm_k<<<BQ, blk, 0, stream>>>(hidden, ln1w, ln1b, xb);
  // q,k,v fused GEMM (q scaled 0.125 in epilogue)
  gemm_lds<128, 128, 3><<<gqkv, blk, 0, stream>>>(xb, wq, q_b, nullptr,
      qb, kb, vb, k_b, v_b, 3840, HIDn, 1.f);
  // present kv
  copy_present<<<(Bc * Hn * Cn * 8 + 255) / 256, blk, 0, stream>>>(kb, vb, out_pk, out_pv);
  // self attention -> ab
  attn_mfma<true><<<gattn, blk, 0, stream>>>(qb, past_k, past_v, kb, vb, mask, ab, Cn, KSELF);
  // h1 = hidden + ab Wo^T + bo
  gemm_lds<64, 64, 0><<<g64, blk, 0, stream>>>(ab, wo, o_b, hidden,
      h1, nullptr, nullptr, nullptr, nullptr, HIDn, HIDn, 1.f);
  // x2 = LN2(h1)
  layernorm_k<<<BQ, blk, 0, stream>>>(h1, ln2w, ln2b, xb);
  // cq = (x2 Wcq^T + b)*0.125  (reuse qb)
  gemm_lds<64, 64, 1><<<g64, blk, 0, stream>>>(xb, wcq, cq_b, nullptr,
      qb, nullptr, nullptr, nullptr, nullptr, HIDn, HIDn, 0.125f);
  // cross attention -> ab
  attn_mfma<false><<<gattn, blk, 0, stream>>>(qb, cross_k, cross_v,
      (const short*)nullptr, (const short*)nullptr, nullptr, ab, En, En);
  // h2 = h1 + ab Wco^T + b
  gemm_lds<64, 64, 0><<<g64, blk, 0, stream>>>(ab, wco, co_b, h1,
      h2, nullptr, nullptr, nullptr, nullptr, HIDn, HIDn, 1.f);
  // x3 = LN3(h2)
  layernorm_k<<<BQ, blk, 0, stream>>>(h2, ln3w, ln3b, xb);
  // upa = gelu(x3 Wup^T + b)
  gemm_lds<128, 128, 2><<<gup, blk, 0, stream>>>(xb, wup, up_b, nullptr,
      upa, nullptr, nullptr, nullptr, nullptr, In, HIDn, 1.f);
  // out_h = h2 + upa Wdn^T + b
  gemm_lds<64, 64, 0><<<g64, blk, 0, stream>>>(upa, wdn, dn_b, h2,
      out_h, nullptr, nullptr, nullptr, nullptr, HIDn, In, 1.f);
}

// Round 4
// 521.504 us; speedup vs baseline: 3.7260x; 1.0073x over previous
//
#include <hip/hip_runtime.h>
#include <math.h>

// Problem constants
#define Bc   8
#define Qn   256
#define Cn   192
#define Hn   20
#define Dn   64
#define En   1500
#define In   5120
#define HIDn 1280
#define BQ   2048            // B*Q rows
#define KSELF 448            // Q + C
#define S1   (BQ*HIDn)       // 2,621,440
#define WSZ  (HIDn*HIDn)     // 1,638,400

typedef __attribute__((ext_vector_type(8))) short bf16x8;
typedef __attribute__((ext_vector_type(4))) float f32x4;

__device__ __forceinline__ short f2bf(float f) {
  union { float f; unsigned u; } x; x.f = f;
  unsigned r = x.u + 0x7fffu + ((x.u >> 16) & 1u);   // RNE
  return (short)(r >> 16);
}
__device__ __forceinline__ float bf2f(short s) {
  union { unsigned u; float f; } x; x.u = ((unsigned)(unsigned short)s) << 16;
  return x.f;
}
__device__ __forceinline__ void gload16(const short* g, short* l) {
  __builtin_amdgcn_global_load_lds(
      (const __attribute__((address_space(1))) void*)g,
      (__attribute__((address_space(3))) void*)l, 16, 0, 0);
}

// ---------------------------------------------------------------------------
// Convert all 8 weight matrices fp32 -> bf16 (blockIdx.y selects matrix)
// ---------------------------------------------------------------------------
__global__ __launch_bounds__(256) void convert_all(
    const float* q, const float* k, const float* v, const float* o,
    const float* cq, const float* co, const float* up, const float* dn,
    short* wq, short* wk, short* wv, short* wo,
    short* wcq, short* wco, short* wup, short* wdn)
{
  const float* src; short* dst; int n;
  switch (blockIdx.y) {
    case 0: src = q;  dst = wq;  n = WSZ; break;
    case 1: src = k;  dst = wk;  n = WSZ; break;
    case 2: src = v;  dst = wv;  n = WSZ; break;
    case 3: src = o;  dst = wo;  n = WSZ; break;
    case 4: src = cq; dst = wcq; n = WSZ; break;
    case 5: src = co; dst = wco; n = WSZ; break;
    case 6: src = up; dst = wup; n = HIDn * In; break;
    default: src = dn; dst = wdn; n = HIDn * In; break;
  }
  const int i = (blockIdx.x * 256 + threadIdx.x) * 8;
  if (i >= n) return;
  const float4 a = *reinterpret_cast<const float4*>(src + i);
  const float4 b = *reinterpret_cast<const float4*>(src + i + 4);
  bf16x8 t;
  t[0] = f2bf(a.x); t[1] = f2bf(a.y); t[2] = f2bf(a.z); t[3] = f2bf(a.w);
  t[4] = f2bf(b.x); t[5] = f2bf(b.y); t[6] = f2bf(b.z); t[7] = f2bf(b.w);
  *reinterpret_cast<bf16x8*>(dst + i) = t;
}

// ---------------------------------------------------------------------------
// LayerNorm: fp32 in, bf16 out. One 256-thread block per row of 1280.
// ---------------------------------------------------------------------------
__global__ __launch_bounds__(256) void layernorm_k(
    const float* __restrict__ in, const float* __restrict__ w,
    const float* __restrict__ b, short* __restrict__ out)
{
  const int row = blockIdx.x;
  const float* x = in + (size_t)row * HIDn;
  float v[5], s = 0.f, s2 = 0.f;
#pragma unroll
  for (int i = 0; i < 5; ++i) {
    float t = x[threadIdx.x + 256 * i];
    v[i] = t; s += t; s2 += t * t;
  }
#pragma unroll
  for (int off = 1; off < 64; off <<= 1) {
    s  += __shfl_xor(s,  off, 64);
    s2 += __shfl_xor(s2, off, 64);
  }
  __shared__ float red[8];
  const int wave = threadIdx.x >> 6, lane = threadIdx.x & 63;
  if (lane == 0) { red[wave] = s; red[wave + 4] = s2; }
  __syncthreads();
  s  = red[0] + red[1] + red[2] + red[3];
  s2 = red[4] + red[5] + red[6] + red[7];
  const float mu  = s / HIDn;
  const float var = s2 / HIDn - mu * mu;
  const float rs  = rsqrtf(var + 1e-5f);
#pragma unroll
  for (int i = 0; i < 5; ++i) {
    const int c = threadIdx.x + 256 * i;
    out[(size_t)row * HIDn + c] = f2bf((v[i] - mu) * rs * w[c] + b[c]);
  }
}

// ---------------------------------------------------------------------------
// NT GEMM, bf16 in via global_load_lds, fragment-order LDS, BK=64.
// 4 waves as 2x2; wave computes (BM/2)x(BN/2) via FM x FN 16x16 frags.
// Fragment (rb, kk): rows rb*16..+15, k-half kk*32..+31; stored at
// (rb*2+kk)*512 shorts, lane's 8 shorts at lane*8 (16B/lane -> b128 reads).
// MODE 0: fp32 out = acc + bias + resid
// MODE 1: bf16 out = (acc + bias) * scale
// MODE 2: bf16 out = gelu(acc + bias)
// MODE 3: QKV triple bf16 out; region by n0/1280; q region scaled 0.125
// ---------------------------------------------------------------------------
template<int BM, int BN, int MODE>
__global__ __launch_bounds__(256) void gemm_bk64(
    const short* __restrict__ A, const short* __restrict__ W,
    const float* __restrict__ bias, const float* __restrict__ resid,
    void* __restrict__ out0, void* __restrict__ out1, void* __restrict__ out2,
    const float* __restrict__ b1, const float* __restrict__ b2,
    int N, int K, float scale)
{
  constexpr int FM = BM / 32, FN = BN / 32;
  __shared__ __align__(16) short Alds[BM * 64];
  __shared__ __align__(16) short Blds[BN * 64];
  const int tid = threadIdx.x, lane = tid & 63, wave = tid >> 6;
  const int wr = wave >> 1, wc = wave & 1;
  const int m0 = blockIdx.x * BM, n0 = blockIdx.y * BN;
  const int lr = lane & 15;               // fragment row
  const int kc = (lane >> 4) * 8;         // fragment k sub-offset

  f32x4 acc[FM][FN];
#pragma unroll
  for (int mi = 0; mi < FM; ++mi)
#pragma unroll
    for (int ni = 0; ni < FN; ++ni)
      acc[mi][ni] = (f32x4){0.f, 0.f, 0.f, 0.f};

  const int nk = K >> 6;
  for (int kt = 0; kt < nk; ++kt) {
    const int k0 = kt << 6;
#pragma unroll
    for (int j = 0; j < BM / 32; ++j) {
      const int i = wave + 4 * j;          // issue index in [0, BM/8)
      const int rb = i >> 1, kk = i & 1;
      gload16(A + (size_t)(m0 + rb * 16 + lr) * K + k0 + kk * 32 + kc, &Alds[i * 512]);
    }
#pragma unroll
    for (int j = 0; j < BN / 32; ++j) {
      const int i = wave + 4 * j;
      const int rb = i >> 1, kk = i & 1;
      gload16(W + (size_t)(n0 + rb * 16 + lr) * K + k0 + kk * 32 + kc, &Blds[i * 512]);
    }
    __syncthreads();
    bf16x8 af[2][FM], bfv[2][FN];
#pragma unroll
    for (int kk = 0; kk < 2; ++kk) {
#pragma unroll
      for (int mi = 0; mi < FM; ++mi)
        af[kk][mi] = *reinterpret_cast<const bf16x8*>(
            &Alds[((wr * FM + mi) * 2 + kk) * 512 + lane * 8]);
#pragma unroll
      for (int ni = 0; ni < FN; ++ni)
        bfv[kk][ni] = *reinterpret_cast<const bf16x8*>(
            &Blds[((wc * FN + ni) * 2 + kk) * 512 + lane * 8]);
    }
#pragma unroll
    for (int kk = 0; kk < 2; ++kk)
#pragma unroll
      for (int mi = 0; mi < FM; ++mi)
#pragma unroll
        for (int ni = 0; ni < FN; ++ni)
          acc[mi][ni] = __builtin_amdgcn_mfma_f32_16x16x32_bf16(
              af[kk][mi], bfv[kk][ni], acc[mi][ni], 0, 0, 0);
    __syncthreads();
  }

  // epilogue: C/D col = lane&15, row = (lane>>4)*4 + reg
  const int cn = lane & 15;
  const int rb = (lane >> 4) * 4;
#pragma unroll
  for (int mi = 0; mi < FM; ++mi)
#pragma unroll
    for (int ni = 0; ni < FN; ++ni)
#pragma unroll
      for (int j = 0; j < 4; ++j) {
        const int row = m0 + wr * (BM / 2) + mi * 16 + rb + j;
        const int col = n0 + wc * (BN / 2) + ni * 16 + cn;
        const float a = acc[mi][ni][j];
        if (MODE == 0) {
          ((float*)out0)[(size_t)row * N + col] =
              a + bias[col] + resid[(size_t)row * N + col];
        } else if (MODE == 1) {
          ((short*)out0)[(size_t)row * N + col] = f2bf((a + bias[col]) * scale);
        } else if (MODE == 2) {
          float t = a + bias[col];
          t = 0.5f * t * (1.f + erff(t * 0.70710678118654752f));
          ((short*)out0)[(size_t)row * N + col] = f2bf(t);
        } else {
          const int rg  = n0 / 1280;
          const int cl  = col - rg * 1280;
          short* op     = rg == 0 ? (short*)out0 : rg == 1 ? (short*)out1 : (short*)out2;
          const float* bp = rg == 0 ? bias : rg == 1 ? b1 : b2;
          const float sc  = rg == 0 ? 0.125f : 1.f;
          op[(size_t)row * 1280 + cl] = f2bf((a + bp[cl]) * sc);
        }
      }
}

// ---------------------------------------------------------------------------
// MFMA flash attention. Q/Kn/Vn/out bf16; past/cross K/V fp32.
// 1-D grid of 640 blocks, XCD-chunk swizzled so the 4 q-tiles of one (b,h)
// land on the same XCD (L2 reuse of the K/V panel).
// Block = 4 waves; each wave owns 16 q-rows of a 64-row Q tile; 64-key chunks.
// ---------------------------------------------------------------------------
template<bool HASMASK>
__global__ __launch_bounds__(256) void attn_mfma(
    const short* __restrict__ Qb, const float* __restrict__ Kp,
    const float* __restrict__ Vp, const short* __restrict__ Kn,
    const short* __restrict__ Vn, const float* __restrict__ mask,
    short* __restrict__ Ob, int Cp, int KT)
{
  const int orig = blockIdx.x;                  // 640 = 4*Hn*Bc
  const int idx  = (orig & 7) * 80 + (orig >> 3);
  const int qt = idx & 3;
  const int h  = (idx >> 2) % Hn;
  const int b  = idx / (4 * Hn);
  const int tid = threadIdx.x, lane = tid & 63, wave = tid >> 6;
  const int q0 = qt * 64;
  const int cn = lane & 15;
  const int hg = lane >> 4;
  const int rb = hg * 4;

  __shared__ __align__(16) short k_s[64][72];
  __shared__ __align__(16) short vt_s[64][72];
  __shared__ __align__(16) short p_s[4][16][72];

  bf16x8 aq[2];
  {
    const short* qrow = Qb + (size_t)(b * Qn + q0 + wave * 16 + cn) * HIDn + h * 64;
    aq[0] = *reinterpret_cast<const bf16x8*>(qrow + hg * 8);
    aq[1] = *reinterpret_cast<const bf16x8*>(qrow + 32 + hg * 8);
  }

  float mrun[4] = {-1e30f, -1e30f, -1e30f, -1e30f};
  float lrun[4] = {0.f, 0.f, 0.f, 0.f};
  f32x4 oacc[4];
#pragma unroll
  for (int t = 0; t < 4; ++t) oacc[t] = (f32x4){0.f, 0.f, 0.f, 0.f};

  const int nchunk = (KT + 63) >> 6;
  for (int ci = 0; ci < nchunk; ++ci) {
    const int c0 = ci * 64;
    // stage K row-major + V transposed/swizzled, 8-elem chunks
    for (int i = tid; i < 64 * 8; i += 256) {
      const int key = i >> 3, d8 = (i & 7) * 8;
      const int gk = c0 + key;
      bf16x8 kv8 = (bf16x8)0, vv8 = (bf16x8)0;
      if (gk < KT) {
        if (gk < Cp) {
          const size_t off = (((size_t)b * Hn + h) * (size_t)Cp + gk) * 64 + d8;
          const float4 ka = *reinterpret_cast<const float4*>(Kp + off);
          const float4 kb = *reinterpret_cast<const float4*>(Kp + off + 4);
          const float4 va = *reinterpret_cast<const float4*>(Vp + off);
          const float4 vb = *reinterpret_cast<const float4*>(Vp + off + 4);
          kv8[0] = f2bf(ka.x); kv8[1] = f2bf(ka.y); kv8[2] = f2bf(ka.z); kv8[3] = f2bf(ka.w);
          kv8[4] = f2bf(kb.x); kv8[5] = f2bf(kb.y); kv8[6] = f2bf(kb.z); kv8[7] = f2bf(kb.w);
          vv8[0] = f2bf(va.x); vv8[1] = f2bf(va.y); vv8[2] = f2bf(va.z); vv8[3] = f2bf(va.w);
          vv8[4] = f2bf(vb.x); vv8[5] = f2bf(vb.y); vv8[6] = f2bf(vb.z); vv8[7] = f2bf(vb.w);
        } else {
          const size_t off = (size_t)(b * Qn + (gk - Cp)) * HIDn + h * 64 + d8;
          kv8 = *reinterpret_cast<const bf16x8*>(Kn + off);
          vv8 = *reinterpret_cast<const bf16x8*>(Vn + off);
        }
      }
      *reinterpret_cast<bf16x8*>(&k_s[key][d8]) = kv8;
      const int g = key >> 3, o = key & 7, f = (d8 >> 3) & 7;
#pragma unroll
      for (int j = 0; j < 8; ++j)
        vt_s[d8 + j][((g ^ f) << 3) | o] = vv8[j];
    }
    __syncthreads();

    // QK^T
    f32x4 sacc[4];
#pragma unroll
    for (int t = 0; t < 4; ++t) sacc[t] = (f32x4){0.f, 0.f, 0.f, 0.f};
#pragma unroll
    for (int t = 0; t < 4; ++t)
#pragma unroll
      for (int kk = 0; kk < 2; ++kk) {
        const bf16x8 bk = *reinterpret_cast<const bf16x8*>(&k_s[t * 16 + cn][kk * 32 + hg * 8]);
        sacc[t] = __builtin_amdgcn_mfma_f32_16x16x32_bf16(aq[kk], bk, sacc[t], 0, 0, 0);
      }

    float sc[4][4];
#pragma unroll
    for (int t = 0; t < 4; ++t) {
      const int key = c0 + t * 16 + cn;
      const bool valid = key < KT;
#pragma unroll
      for (int j = 0; j < 4; ++j) {
        float v = sacc[t][j];
        if (HASMASK && valid)
          v += mask[((size_t)(b * Qn) + q0 + wave * 16 + rb + j) * KT + key];
        sc[t][j] = valid ? v : -1e30f;
      }
    }

    // online softmax
#pragma unroll
    for (int j = 0; j < 4; ++j) {
      float mx = fmaxf(fmaxf(sc[0][j], sc[1][j]), fmaxf(sc[2][j], sc[3][j]));
#pragma unroll
      for (int off = 1; off < 16; off <<= 1) mx = fmaxf(mx, __shfl_xor(mx, off, 64));
      const float mnew  = fmaxf(mrun[j], mx);
      const float alpha = __expf(mrun[j] - mnew);
      float ps = 0.f;
#pragma unroll
      for (int t = 0; t < 4; ++t) {
        const float p = __expf(sc[t][j] - mnew);
        sc[t][j] = p; ps += p;
      }
#pragma unroll
      for (int off = 1; off < 16; off <<= 1) ps += __shfl_xor(ps, off, 64);
      lrun[j] = lrun[j] * alpha + ps;
      mrun[j] = mnew;
#pragma unroll
      for (int t = 0; t < 4; ++t) oacc[t][j] *= alpha;
    }

    // P -> per-wave LDS slice (same-wave RAW)
#pragma unroll
    for (int t = 0; t < 4; ++t)
#pragma unroll
      for (int j = 0; j < 4; ++j)
        p_s[wave][rb + j][t * 16 + cn] = f2bf(sc[t][j]);

    // PV
    const bf16x8 ap0 = *reinterpret_cast<const bf16x8*>(&p_s[wave][cn][hg * 8]);
    const bf16x8 ap1 = *reinterpret_cast<const bf16x8*>(&p_s[wave][cn][32 + hg * 8]);
#pragma unroll
    for (int t = 0; t < 4; ++t) {
      const int d  = t * 16 + cn;
      const int fd = (d >> 3) & 7;
      const bf16x8 bv0 = *reinterpret_cast<const bf16x8*>(&vt_s[d][((hg)     ^ fd) << 3]);
      const bf16x8 bv1 = *reinterpret_cast<const bf16x8*>(&vt_s[d][((4 + hg) ^ fd) << 3]);
      oacc[t] = __builtin_amdgcn_mfma_f32_16x16x32_bf16(ap0, bv0, oacc[t], 0, 0, 0);
      oacc[t] = __builtin_amdgcn_mfma_f32_16x16x32_bf16(ap1, bv1, oacc[t], 0, 0, 0);
    }
    __syncthreads();
  }

#pragma unroll
  for (int t = 0; t < 4; ++t)
#pragma unroll
    for (int j = 0; j < 4; ++j)
      Ob[(size_t)(b * Qn + q0 + wave * 16 + rb + j) * HIDn + h * 64 + t * 16 + cn] =
          f2bf(oacc[t][j] / lrun[j]);
}

// ---------------------------------------------------------------------------
// present_key/value: bf16 new K/V rows (Q-C)..Q-1 -> fp32 (B,H,C,D)
// ---------------------------------------------------------------------------
__global__ __launch_bounds__(256) void copy_present(
    const short* __restrict__ kn, const short* __restrict__ vn,
    float* __restrict__ outk, float* __restrict__ outv)
{
  const int idx = blockIdx.x * 256 + threadIdx.x;      // over B*H*C*8 chunks
  if (idx >= Bc * Hn * Cn * 8) return;
  const int d8 = (idx & 7) * 8;
  int t = idx >> 3;
  const int c = t % Cn; t /= Cn;
  const int h = t % Hn;
  const int b = t / Hn;
  const size_t src = (size_t)(b * Qn + (Qn - Cn) + c) * HIDn + h * 64 + d8;
  const size_t dst = (((size_t)b * Hn + h) * Cn + c) * 64 + d8;
  const bf16x8 kv = *reinterpret_cast<const bf16x8*>(kn + src);
  const bf16x8 vv = *reinterpret_cast<const bf16x8*>(vn + src);
#pragma unroll
  for (int j = 0; j < 8; ++j) {
    outk[dst + j] = bf2f(kv[j]);
    outv[dst + j] = bf2f(vv[j]);
  }
}

// ---------------------------------------------------------------------------
extern "C" void kernel_launch(void* const* d_in, const int* in_sizes, int n_in,
                              void* d_out, int out_size, void* d_ws, size_t ws_size,
                              hipStream_t stream)
{
  const float* hidden  = (const float*)d_in[0];
  const float* mask    = (const float*)d_in[1];
  const float* past_k  = (const float*)d_in[2];
  const float* past_v  = (const float*)d_in[3];
  const float* cross_k = (const float*)d_in[4];
  const float* cross_v = (const float*)d_in[5];
  const float* q_w  = (const float*)d_in[6];  const float* q_b  = (const float*)d_in[7];
  const float* k_w  = (const float*)d_in[8];  const float* k_b  = (const float*)d_in[9];
  const float* v_w  = (const float*)d_in[10]; const float* v_b  = (const float*)d_in[11];
  const float* o_w  = (const float*)d_in[12]; const float* o_b  = (const float*)d_in[13];
  const float* cq_w = (const float*)d_in[14]; const float* cq_b = (const float*)d_in[15];
  const float* co_w = (const float*)d_in[16]; const float* co_b = (const float*)d_in[17];
  const float* up_w = (const float*)d_in[18]; const float* up_b = (const float*)d_in[19];
  const float* dn_w = (const float*)d_in[20]; const float* dn_b = (const float*)d_in[21];
  const float* ln1w = (const float*)d_in[22]; const float* ln1b = (const float*)d_in[23];
  const float* ln2w = (const float*)d_in[24]; const float* ln2b = (const float*)d_in[25];
  const float* ln3w = (const float*)d_in[26]; const float* ln3b = (const float*)d_in[27];

  // workspace layout (bf16 weights, bf16 activations, fp32 residuals)
  short* wq  = (short*)d_ws;                    // qkv weights contiguous
  short* wk  = wq  + (size_t)WSZ;
  short* wv  = wk  + (size_t)WSZ;
  short* wo  = wv  + (size_t)WSZ;
  short* wcq = wo  + (size_t)WSZ;
  short* wco = wcq + (size_t)WSZ;
  short* wup = wco + (size_t)WSZ;
  short* wdn = wup + (size_t)HIDn * In;
  short* xb  = wdn + (size_t)HIDn * In;         // LN outputs (reused x1,x2,x3)
  short* qb  = xb  + (size_t)S1;                // q, reused as cq
  short* kb  = qb  + (size_t)S1;
  short* vb  = kb  + (size_t)S1;
  short* ab  = vb  + (size_t)S1;                // attn outputs
  short* upa = ab  + (size_t)S1;                // gelu(up) activations
  float* h1  = (float*)(upa + (size_t)BQ * In);
  float* h2  = h1 + (size_t)S1;

  float* out_h  = (float*)d_out;
  float* out_pk = out_h + (size_t)S1;
  float* out_pv = out_pk + (size_t)(Bc * Hn * Cn * Dn);

  const dim3 blk(256);
  const dim3 gconv(3200, 8);
  const dim3 gqkv(16, 30);         // 2048/128 x 3840/128
  const dim3 gn64(16, 20);         // 2048/128 x 1280/64
  const dim3 gup(16, 40);          // 2048/128 x 5120/128
  const dim3 gattn(640);           // 4 * Hn * Bc, XCD-swizzled in-kernel

  // weights -> bf16
  convert_all<<<gconv, blk, 0, stream>>>(q_w, k_w, v_w, o_w, cq_w, co_w, up_w, dn_w,
                                         wq, wk, wv, wo, wcq, wco, wup, wdn);
  // x1 = LN1(hidden)
  layernorm_k<<<BQ, blk, 0, stream>>>(hidden, ln1w, ln1b, xb);
  // q,k,v fused GEMM (q scaled 0.125 in epilogue)
  gemm_bk64<128, 128, 3><<<gqkv, blk, 0, stream>>>(xb, wq, q_b, nullptr,
      qb, kb, vb, k_b, v_b, 3840, HIDn, 1.f);
  // present kv
  copy_present<<<(Bc * Hn * Cn * 8 + 255) / 256, blk, 0, stream>>>(kb, vb, out_pk, out_pv);
  // self attention -> ab
  attn_mfma<true><<<gattn, blk, 0, stream>>>(qb, past_k, past_v, kb, vb, mask, ab, Cn, KSELF);
  // h1 = hidden + ab Wo^T + bo
  gemm_bk64<128, 64, 0><<<gn64, blk, 0, stream>>>(ab, wo, o_b, hidden,
      h1, nullptr, nullptr, nullptr, nullptr, HIDn, HIDn, 1.f);
  // x2 = LN2(h1)
  layernorm_k<<<BQ, blk, 0, stream>>>(h1, ln2w, ln2b, xb);
  // cq = (x2 Wcq^T + b)*0.125  (reuse qb)
  gemm_bk64<128, 64, 1><<<gn64, blk, 0, stream>>>(xb, wcq, cq_b, nullptr,
      qb, nullptr, nullptr, nullptr, nullptr, HIDn, HIDn, 0.125f);
  // cross attention -> ab
  attn_mfma<false><<<gattn, blk, 0, stream>>>(qb, cross_k, cross_v,
      (const short*)nullptr, (const short*)nullptr, nullptr, ab, En, En);
  // h2 = h1 + ab Wco^T + b
  gemm_bk64<128, 64, 0><<<gn64, blk, 0, stream>>>(ab, wco, co_b, h1,
      h2, nullptr, nullptr, nullptr, nullptr, HIDn, HIDn, 1.f);
  // x3 = LN3(h2)
  layernorm_k<<<BQ, blk, 0, stream>>>(h2, ln3w, ln3b, xb);
  // upa = gelu(x3 Wup^T + b)
  gemm_bk64<128, 128, 2><<<gup, blk, 0, stream>>>(xb, wup, up_b, nullptr,
      upa, nullptr, nullptr, nullptr, nullptr, In, HIDn, 1.f);
  // out_h = h2 + upa Wdn^T + b
  gemm_bk64<128, 64, 0><<<gn64, blk, 0, stream>>>(upa, wdn, dn_b, h2,
      out_h, nullptr, nullptr, nullptr, nullptr, HIDn, In, 1.f);
}